// Round 1
// baseline (66.470 us; speedup 1.0000x reference)
//
#include <hip/hip_runtime.h>
#include <stdint.h>

#define N_   64
#define C_   64
#define W_   4096
#define F_   64
#define WW_  9
#define OW_  4088        // W_ - WW_ + 1
#define WBLK 128
#define WROWS 136        // WBLK + 8 halo
#define NWB  32          // ceil(OW_/WBLK)

typedef __bf16 bf16x8 __attribute__((ext_vector_type(8)));
typedef float  f32x4  __attribute__((ext_vector_type(4)));

__device__ __forceinline__ unsigned short f2bf(float f) {
    union { float f; uint32_t u; } v; v.f = f;
    uint32_t u = v.u;
    return (unsigned short)((u + 0x7FFFu + ((u >> 16) & 1u)) >> 16);  // RNE
}

// filt fp32 [F][C][WW]  ->  filtT bf16 [t][f][c]  (so B-fragments are 16B-contiguous in c)
__global__ __launch_bounds__(256) void prep_filt_k(const float* __restrict__ filt,
                                                   unsigned short* __restrict__ filtT) {
    int id = blockIdx.x * 256 + threadIdx.x;
    if (id < WW_ * F_ * C_) {
        int t   = id >> 12;       // / (64*64)
        int rem = id & 4095;
        int f   = rem >> 6;
        int c   = rem & 63;
        filtT[id] = f2bf(filt[(f * C_ + c) * WW_ + t]);
    }
}

// One block: n = blockIdx.y, w-block of 128 outputs, all 64 filters.
// 4 waves; wave (wv): f-half = (wv&1)*32, w-half = (wv>>1)*64.
// out[n,f,w] = sum_{t,c} x[n,c,w+t]*filt[f,c,t] + 64*bias[f]
__global__ __launch_bounds__(256) void conv_main_k(const float* __restrict__ x,
                                                   const unsigned short* __restrict__ filtT,
                                                   const float* __restrict__ bias,
                                                   float* __restrict__ out) {
    // LDS x-tile, transposed [w_local][c] bf16, rows = 128B, XOR-swizzled 16B chunks
    __shared__ unsigned short xs[WROWS * 64];

    const int tid = threadIdx.x;
    const int n   = blockIdx.y;
    const int w0  = blockIdx.x * WBLK;

    // ---- stage: read x[n, c, w0 .. w0+135] coalesced (float4 along w), write transposed bf16 ----
    // 64 c-rows * 34 float4 = 2176 float4 units
    #pragma unroll
    for (int i = 0; i < 9; ++i) {
        int e4 = i * 256 + tid;
        if (e4 < 34 * 64) {
            int c  = e4 / 34;
            int w4 = e4 - c * 34;
            int wl = w4 * 4;
            int gw = w0 + wl;
            const float* xp = x + ((n * C_ + c) * W_ + gw);
            float4 v;
            if (gw + 3 < W_) {
                v = *reinterpret_cast<const float4*>(xp);
            } else {                       // only last w-block: zero-fill halo past W
                v.x = (gw + 0 < W_) ? xp[0] : 0.0f;
                v.y = (gw + 1 < W_) ? xp[1] : 0.0f;
                v.z = (gw + 2 < W_) ? xp[2] : 0.0f;
                v.w = (gw + 3 < W_) ? xp[3] : 0.0f;
            }
            unsigned short h[4] = { f2bf(v.x), f2bf(v.y), f2bf(v.z), f2bf(v.w) };
            #pragma unroll
            for (int j = 0; j < 4; ++j) {
                int w = wl + j;
                // element index: row w (64 ushorts), chunk (c>>3)^(w&7), sub (c&7)
                xs[w * 64 + ((((c >> 3) ^ (w & 7)) << 3) | (c & 7))] = h[j];
            }
        }
    }
    __syncthreads();

    const int lane = tid & 63;
    const int wv   = tid >> 6;
    const int f0   = (wv & 1) * 32;    // this wave's 32-filter half
    const int whb  = (wv >> 1) * 64;   // this wave's 64-w half (local)
    const int l15  = lane & 15;
    const int lg   = lane >> 4;

    f32x4 acc[4][2];
    #pragma unroll
    for (int s = 0; s < 4; ++s)
        #pragma unroll
        for (int u = 0; u < 2; ++u)
            acc[s][u] = (f32x4){0.f, 0.f, 0.f, 0.f};

    // K loop: 9 taps x 2 c-chunks of 32
    #pragma unroll
    for (int t = 0; t < WW_; ++t) {
        #pragma unroll
        for (int m = 0; m < 2; ++m) {
            // B frags (filt), layout [t][f][c]: lane l -> B[k=8*lg+j][col=f0+u*16+l15]
            const unsigned short* bp = filtT + t * (F_ * C_) + (f0 + l15) * C_ + m * 32 + lg * 8;
            bf16x8 b0 = *reinterpret_cast<const bf16x8*>(bp);
            bf16x8 b1 = *reinterpret_cast<const bf16x8*>(bp + 16 * C_);
            #pragma unroll
            for (int s = 0; s < 4; ++s) {
                int row   = whb + s * 16 + l15 + t;              // <= 135
                int chunk = ((m << 2) + lg) ^ (row & 7);
                bf16x8 a  = *reinterpret_cast<const bf16x8*>(&xs[row * 64 + chunk * 8]);
                acc[s][0] = __builtin_amdgcn_mfma_f32_16x16x32_bf16(a, b0, acc[s][0], 0, 0, 0);
                acc[s][1] = __builtin_amdgcn_mfma_f32_16x16x32_bf16(a, b1, acc[s][1], 0, 0, 0);
            }
        }
    }

    // ---- epilogue: D layout col=f=lane&15, row=w=(lane>>4)*4+r ; fused bias; float4 stores ----
    #pragma unroll
    for (int u = 0; u < 2; ++u) {
        int f = f0 + u * 16 + l15;
        float bv = 64.0f * bias[f];    // reference adds bias once per channel -> C*bias
        #pragma unroll
        for (int s = 0; s < 4; ++s) {
            int wg = w0 + whb + s * 16 + lg * 4;
            if (wg < OW_) {            // wg%4==0 and OW_%4==0 -> whole float4 in-range
                float4 o;
                o.x = acc[s][u][0] + bv;
                o.y = acc[s][u][1] + bv;
                o.z = acc[s][u][2] + bv;
                o.w = acc[s][u][3] + bv;
                *reinterpret_cast<float4*>(out + ((n * F_ + f) * OW_ + wg)) = o;
            }
        }
    }
}

extern "C" void kernel_launch(void* const* d_in, const int* in_sizes, int n_in,
                              void* d_out, int out_size, void* d_ws, size_t ws_size,
                              hipStream_t stream) {
    const float* x    = (const float*)d_in[0];
    const float* filt = (const float*)d_in[1];
    const float* bias = (const float*)d_in[2];
    float* out        = (float*)d_out;
    unsigned short* filtT = (unsigned short*)d_ws;   // 9*64*64 bf16 = 73728 B

    prep_filt_k<<<(WW_ * F_ * C_ + 255) / 256, 256, 0, stream>>>(filt, filtT);

    dim3 grid(NWB, N_);
    conv_main_k<<<grid, 256, 0, stream>>>(x, filtT, bias, out);
}